// Round 1
// baseline (345.522 us; speedup 1.0000x reference)
//
#include <hip/hip_runtime.h>
#include <math.h>

// Problem constants
#define BATCH 64
#define NPTS  2048
// ws float offsets (total 176256 floats = 706 KB)
#define OFF_M   0        // [64][61]  M[b][c*6+a], Sdw at [b][60]
#define OFF_T2  4096     // [64][18]  T2[m][a*3+j]
#define OFF_V   8192     // [384][128] V[ma][v]
#define OFF_D2  57344    // [64][256]
#define OFF_Z   73728    // [64][128]
#define OFF_C2  81920    // [64][64]  center2[b][m]
#define OFF_U2  86016    // [384][64] U2[ma][b]
#define OFF_GP  110592   // [512][128] per-block bn3 partials
#define OFF_SO  176128   // [128] scale[64], offset[64]

// ---------------------------------------------------------------------------
// Fold Wm0 through Wdc:  T2[m][a*3+j] = sum_e Wm0[m,e]*Wdc[e*6+a, j]
//                        V[m*6+a][v]  = sum_e Wm0[m,e]*Wdc[e*6+a, 3+v]
__global__ __launch_bounds__(256) void k_w2(const float* __restrict__ Wm0,
                                            const float* __restrict__ Wdc,
                                            float* __restrict__ ws) {
    int idx = blockIdx.x * 256 + threadIdx.x;
    if (idx < 384 * 128) {
        int ma = idx >> 7, v = idx & 127;
        int a = ma % 6;
        const float* wm = Wm0 + (ma / 6) * 256;
        float s = 0.f;
        for (int e = 0; e < 256; ++e)
            s = fmaf(wm[e], Wdc[(e * 6 + a) * 131 + 3 + v], s);
        ws[OFF_V + ma * 128 + v] = s;
    } else if (idx < 384 * 128 + 64 * 18) {
        int j2 = idx - 384 * 128;
        int m = j2 / 18, r = j2 % 18;
        int a = r / 3, j = r % 3;
        const float* wm = Wm0 + m * 256;
        float s = 0.f;
        for (int e = 0; e < 256; ++e)
            s = fmaf(wm[e], Wdc[(e * 6 + a) * 131 + j], s);
        ws[OFF_T2 + m * 18 + r] = s;
    }
}

// ---------------------------------------------------------------------------
// Stage A: per-batch moments for aggregate().
// M[b][c*6+a] = sum_n dir_in[c]*cos2[a]*dw ;  Sdw[b] = sum_n dw
// One block per b, direct writes (no atomics, no memset needed).
__global__ __launch_bounds__(256) void k_a(const float* __restrict__ x,
                                           float* __restrict__ ws) {
    __shared__ float red[61 * 257];
    int b = blockIdx.x, t = threadIdx.x;
    float acc[61];
#pragma unroll
    for (int i = 0; i < 61; ++i) acc[i] = 0.f;
    for (int k = 0; k < 8; ++k) {
        int n = t + 256 * k;
        const float* xp = x + (size_t)(b * NPTS + n) * 10;
        float xv[10];
#pragma unroll
        for (int j = 0; j < 5; ++j) {
            float2 v = *(const float2*)(xp + 2 * j);
            xv[2 * j] = v.x; xv[2 * j + 1] = v.y;
        }
        float x0 = xv[0], x1 = xv[1], x2 = xv[2];
        float rn = x0 * x0 + x1 * x1 + x2 * x2;
        float norm = sqrtf(rn);
        float inv = 1.f / (norm + 1e-8f);
        float c2[6];
        c2[0] = fmaxf(x2, 0.f) * inv; c2[1] = fmaxf(-x2, 0.f) * inv;
        c2[2] = fmaxf(x1, 0.f) * inv; c2[3] = fmaxf(-x1, 0.f) * inv;
        c2[4] = fmaxf(x0, 0.f) * inv; c2[5] = fmaxf(-x0, 0.f) * inv;
#pragma unroll
        for (int a = 0; a < 6; ++a) c2[a] *= c2[a];
        float dw = 1.f - (rn - 1.f) * (1.f / 3.f);
        if (dw < 0.f) dw = 0.f;
        if (norm <= 0.f) dw = 0.f;
        float cw[6];
#pragma unroll
        for (int a = 0; a < 6; ++a) cw[a] = c2[a] * dw;
        // dir_in = [points(7), xyz(3)]
#pragma unroll
        for (int c = 0; c < 10; ++c) {
            float dv = (c < 7) ? xv[3 + c] : xv[c - 7];
#pragma unroll
            for (int a = 0; a < 6; ++a)
                acc[c * 6 + a] = fmaf(dv, cw[a], acc[c * 6 + a]);
        }
        acc[60] += dw;
    }
#pragma unroll
    for (int i = 0; i < 61; ++i) red[i * 257 + t] = acc[i];
    __syncthreads();
    if (t < 61) {
        float s = 0.f;
        for (int j = 0; j < 256; ++j) s += red[t * 257 + j];
        ws[OFF_M + b * 61 + t] = s;
    }
}

// ---------------------------------------------------------------------------
// Stage B1: agg[b][m] = (sum_{c,a} Wdir[(m*6+a)*10+c] * M[b][c*6+a]) / Sdw[b]
// then BN1(+relu) over b, then d2 = h1 @ Wdir2.T (this block's 32 e-columns).
__global__ __launch_bounds__(256) void k_b1(const float* __restrict__ Wdir,
                                            const float* __restrict__ g1,
                                            const float* __restrict__ b1,
                                            const float* __restrict__ Wdir2,
                                            float* __restrict__ ws) {
    __shared__ float h1[64 * 64];
    __shared__ float sc[64], of[64];
    int t = threadIdx.x;
#pragma unroll
    for (int k = 0; k < 16; ++k) {
        int e0 = t + 256 * k;
        int b = e0 >> 6, m = e0 & 63;
        const float* Mb = ws + OFF_M + b * 61;
        float s = 0.f;
#pragma unroll
        for (int c = 0; c < 10; ++c)
#pragma unroll
            for (int a = 0; a < 6; ++a)
                s = fmaf(Wdir[(m * 6 + a) * 10 + c], Mb[c * 6 + a], s);
        h1[e0] = s / Mb[60];
    }
    __syncthreads();
    if (t < 64) {
        float s = 0.f, q = 0.f;
        for (int b = 0; b < 64; ++b) { float v = h1[b * 64 + t]; s += v; q += v * v; }
        float mean = s * (1.f / 64.f);
        float var = q * (1.f / 64.f) - mean * mean;
        float scale = g1[t] * rsqrtf(var + 1e-5f);
        sc[t] = scale; of[t] = b1[t] - mean * scale;
    }
    __syncthreads();
#pragma unroll
    for (int k = 0; k < 16; ++k) {
        int e0 = t + 256 * k;
        int m = e0 & 63;
        h1[e0] = fmaxf(fmaf(h1[e0], sc[m], of[m]), 0.f);
    }
    __syncthreads();
    int e = blockIdx.x * 32 + (t & 31);
    int b0 = t >> 5;
    const float* w = Wdir2 + e * 64;
#pragma unroll
    for (int k = 0; k < 8; ++k) {
        int b = b0 + 8 * k;
        const float* h = h1 + b * 64;
        float s = 0.f;
#pragma unroll
        for (int m = 0; m < 64; ++m) s = fmaf(h[m], w[m], s);
        ws[OFF_D2 + b * 256 + e] = s;
    }
}

// ---------------------------------------------------------------------------
// Stage B2: BN2(+relu) over b of d2, then z = enc @ Wf1.T + bf1 (16 v-cols/block).
__global__ __launch_bounds__(256) void k_b2(const float* __restrict__ g2,
                                            const float* __restrict__ b2,
                                            const float* __restrict__ Wf1,
                                            const float* __restrict__ bf1,
                                            float* __restrict__ ws) {
    __shared__ float sc[256], of[256];
    int t = threadIdx.x;
    {
        float s = 0.f, q = 0.f;
        for (int b = 0; b < 64; ++b) { float v = ws[OFF_D2 + b * 256 + t]; s += v; q += v * v; }
        float mean = s * (1.f / 64.f);
        float var = q * (1.f / 64.f) - mean * mean;
        float scale = g2[t] * rsqrtf(var + 1e-5f);
        sc[t] = scale; of[t] = b2[t] - mean * scale;
    }
    __syncthreads();
    int v = blockIdx.x * 16 + (t & 15);
    int b0 = t >> 4;
    const float* w = Wf1 + v * 256;
#pragma unroll
    for (int k = 0; k < 4; ++k) {
        int b = b0 + 16 * k;
        const float* d = ws + OFF_D2 + b * 256;
        float s = bf1[v];
        for (int e = 0; e < 256; ++e) {
            float enc = fmaxf(fmaf(d[e], sc[e], of[e]), 0.f);
            s = fmaf(enc, w[e], s);
        }
        ws[OFF_Z + b * 128 + v] = s;
    }
}

// ---------------------------------------------------------------------------
// U2[ma][b] = sum_v z[b][v]*V[ma][v]   and   center2[b][m] = [z,xyz0]@Wcm.T+bcm
__global__ __launch_bounds__(256) void k_u(const float* __restrict__ x,
                                           const float* __restrict__ Wcm,
                                           const float* __restrict__ bcm,
                                           float* __restrict__ ws) {
    int idx = blockIdx.x * 256 + threadIdx.x;
    if (idx < 384 * 64) {
        int ma = idx >> 6, b = idx & 63;
        const float* z = ws + OFF_Z + b * 128;
        const float* v = ws + OFF_V + ma * 128;   // wave-uniform row -> scalar loads
        float s = 0.f;
#pragma unroll 4
        for (int i = 0; i < 128; ++i) s = fmaf(z[i], v[i], s);
        ws[OFF_U2 + ma * 64 + b] = s;
    } else if (idx < 384 * 64 + 64 * 64) {
        int j = idx - 384 * 64;
        int m = j & 63, b = j >> 6;
        const float* z = ws + OFF_Z + b * 128;    // wave-uniform -> scalar loads
        const float* w = Wcm + m * 131;
        float s = bcm[m];
        for (int i = 0; i < 128; ++i) s = fmaf(z[i], w[i], s);
        const float* xp = x + (size_t)b * NPTS * 10;
        s = fmaf(xp[0], w[128], s);
        s = fmaf(xp[1], w[129], s);
        s = fmaf(xp[2], w[130], s);
        ws[OFF_C2 + b * 64 + m] = s;
    }
}

// ---------------------------------------------------------------------------
// Stage C: bn3 statistics. Block = (b, chunk of 256 points); lane = channel m,
// wave group g owns 64 points -> per-thread scalar accumulators, no shuffles.
// sig2[b,n,m] = sum_a cos2[a]*(xyz . T2[m,a] + U2[b,m,a]); n==0 row -> center2.
__global__ __launch_bounds__(256) void k_c(const float* __restrict__ x,
                                           float* __restrict__ ws) {
    __shared__ float r2[512];
    int blk = blockIdx.x;
    int b = blk >> 3, c = blk & 7;
    int t = threadIdx.x;
    int m = t & 63;
    int g = __builtin_amdgcn_readfirstlane(t >> 6);
    float T[18], U[6];
    const float* t2 = ws + OFF_T2 + m * 18;
#pragma unroll
    for (int r = 0; r < 18; ++r) T[r] = t2[r];
#pragma unroll
    for (int a = 0; a < 6; ++a) U[a] = ws[OFF_U2 + (m * 6 + a) * 64 + b];
    bool has0 = (c == 0) && (g == 0);
    float c2v = 0.f;
    if (has0) c2v = ws[OFF_C2 + b * 64 + m];
    float accS = 0.f, accQ = 0.f;
    int p0 = c * 256 + g * 64;
    const float* xb = x + (size_t)b * NPTS * 10;
    for (int i = 0; i < 64; ++i) {
        const float* xp = xb + (p0 + i) * 10;     // wave-uniform address
        float x0 = xp[0], x1 = xp[1], x2 = xp[2];
        float rn = x0 * x0 + x1 * x1 + x2 * x2;
        float inv = 1.f / (sqrtf(rn) + 1e-8f);
        float c2[6];
        c2[0] = fmaxf(x2, 0.f) * inv; c2[1] = fmaxf(-x2, 0.f) * inv;
        c2[2] = fmaxf(x1, 0.f) * inv; c2[3] = fmaxf(-x1, 0.f) * inv;
        c2[4] = fmaxf(x0, 0.f) * inv; c2[5] = fmaxf(-x0, 0.f) * inv;
        float h = 0.f;
#pragma unroll
        for (int a = 0; a < 6; ++a) {
            float cc = c2[a] * c2[a];
            float ta = fmaf(x0, T[a * 3], fmaf(x1, T[a * 3 + 1], fmaf(x2, T[a * 3 + 2], U[a])));
            h = fmaf(cc, ta, h);
        }
        if (has0 && i == 0) h = c2v;
        accS += h;
        accQ = fmaf(h, h, accQ);
    }
    r2[t] = accS; r2[256 + t] = accQ;
    __syncthreads();
    if (t < 64) {
        ws[OFF_GP + blk * 128 + t] = r2[t] + r2[64 + t] + r2[128 + t] + r2[192 + t];
    } else if (t < 128) {
        int mm = t - 64;
        ws[OFF_GP + blk * 128 + t] = r2[256 + mm] + r2[320 + mm] + r2[384 + mm] + r2[448 + mm];
    }
}

// ---------------------------------------------------------------------------
// Finalize BN3: reduce 512 block partials -> scale/offset per channel.
__global__ void k_fin(const float* __restrict__ g3, const float* __restrict__ b3,
                      float* __restrict__ ws) {
    int t = threadIdx.x;
    if (t >= 64) return;
    float s = 0.f, q = 0.f;
    for (int blk = 0; blk < 512; ++blk) {
        s += ws[OFF_GP + blk * 128 + t];
        q += ws[OFF_GP + blk * 128 + 64 + t];
    }
    float mean = s * (1.f / 131072.f);
    float var = q * (1.f / 131072.f) - mean * mean;
    float scale = g3[t] * rsqrtf(var + 1e-5f);
    ws[OFF_SO + t] = scale;
    ws[OFF_SO + 64 + t] = b3[t] - mean * scale;
}

// ---------------------------------------------------------------------------
// Stage E: recompute sig2 per point, apply BN3+relu, @Wf2.T+bf2, sigmoid.
// Thread = point; m-loop weights are wave-uniform -> scalar loads.
__global__ __launch_bounds__(256) void k_e(const float* __restrict__ x,
                                           const float* __restrict__ Wf2,
                                           const float* __restrict__ bf2,
                                           const float* __restrict__ ws,
                                           float* __restrict__ out) {
    int idx = blockIdx.x * 256 + threadIdx.x;
    int b = idx >> 11, n = idx & 2047;
    const float* xp = x + (size_t)idx * 10;
    float x0 = xp[0], x1 = xp[1], x2 = xp[2];
    float rn = x0 * x0 + x1 * x1 + x2 * x2;
    float inv = 1.f / (sqrtf(rn) + 1e-8f);
    float c2[6];
    c2[0] = fmaxf(x2, 0.f) * inv; c2[1] = fmaxf(-x2, 0.f) * inv;
    c2[2] = fmaxf(x1, 0.f) * inv; c2[3] = fmaxf(-x1, 0.f) * inv;
    c2[4] = fmaxf(x0, 0.f) * inv; c2[5] = fmaxf(-x0, 0.f) * inv;
#pragma unroll
    for (int a = 0; a < 6; ++a) c2[a] *= c2[a];
    bool c0 = (n == 0);
    float y[7];
#pragma unroll
    for (int k = 0; k < 7; ++k) y[k] = bf2[k];
    const float* T2 = ws + OFF_T2;
    const float* U2 = ws + OFF_U2;
    const float* SO = ws + OFF_SO;
    const float* C2W = ws + OFF_C2 + b * 64;
    for (int m = 0; m < 64; ++m) {
        float h = 0.f;
#pragma unroll
        for (int a = 0; a < 6; ++a) {
            float ta = fmaf(x0, T2[m * 18 + a * 3],
                       fmaf(x1, T2[m * 18 + a * 3 + 1],
                       fmaf(x2, T2[m * 18 + a * 3 + 2], U2[(m * 6 + a) * 64 + b])));
            h = fmaf(c2[a], ta, h);
        }
        if (c0) h = C2W[m];
        float tt = fmaf(h, SO[m], SO[64 + m]);
        float r = fmaxf(tt, 0.f);
#pragma unroll
        for (int k = 0; k < 7; ++k) y[k] = fmaf(r, Wf2[k * 64 + m], y[k]);
    }
    float* op = out + (size_t)idx * 7;
#pragma unroll
    for (int k = 0; k < 7; ++k) op[k] = 1.f / (1.f + __expf(-y[k]));
}

// ---------------------------------------------------------------------------
extern "C" void kernel_launch(void* const* d_in, const int* in_sizes, int n_in,
                              void* d_out, int out_size, void* d_ws, size_t ws_size,
                              hipStream_t stream) {
    const float* x     = (const float*)d_in[0];
    // d_in[1]=Wc, d_in[2]=bc : dead code in reference (center is unused)
    const float* Wdir  = (const float*)d_in[3];
    const float* g1    = (const float*)d_in[4];
    const float* b1    = (const float*)d_in[5];
    const float* Wdir2 = (const float*)d_in[6];
    const float* g2    = (const float*)d_in[7];
    const float* b2    = (const float*)d_in[8];
    const float* Wf1   = (const float*)d_in[9];
    const float* bf1   = (const float*)d_in[10];
    const float* Wcm   = (const float*)d_in[11];
    const float* bcm   = (const float*)d_in[12];
    const float* Wdc   = (const float*)d_in[13];
    const float* Wm0   = (const float*)d_in[14];
    const float* g3    = (const float*)d_in[15];
    const float* b3    = (const float*)d_in[16];
    const float* Wf2   = (const float*)d_in[17];
    const float* bf2   = (const float*)d_in[18];
    float* ws  = (float*)d_ws;
    float* out = (float*)d_out;

    k_w2 <<<197, 256, 0, stream>>>(Wm0, Wdc, ws);
    k_a  <<<64,  256, 0, stream>>>(x, ws);
    k_b1 <<<8,   256, 0, stream>>>(Wdir, g1, b1, Wdir2, ws);
    k_b2 <<<8,   256, 0, stream>>>(g2, b2, Wf1, bf1, ws);
    k_u  <<<112, 256, 0, stream>>>(x, Wcm, bcm, ws);
    k_c  <<<512, 256, 0, stream>>>(x, ws);
    k_fin<<<1,   64,  0, stream>>>(g3, b3, ws);
    k_e  <<<512, 256, 0, stream>>>(x, Wf2, bf2, ws, out);
}

// Round 2
// 208.589 us; speedup vs baseline: 1.6565x; 1.6565x over previous
//
#include <hip/hip_runtime.h>
#include <math.h>

// Problem constants
#define BATCH 64
#define NPTS  2048
// ws float offsets (total 176256 floats = 706 KB)
#define OFF_M   0        // [64][61]  M[b][c*6+a], Sdw at [b][60]
#define OFF_T2  4096     // [64][18]  T2[m][a*3+j]
#define OFF_V   8192     // [384][128] V[ma][v]
#define OFF_D2  57344    // [64][256]
#define OFF_Z   73728    // [64][128]
#define OFF_C2  81920    // [64][64]  center2[b][m]
#define OFF_U2  86016    // [384][64] U2[ma][b]
#define OFF_GP  110592   // [512][128] per-block bn3 partials (k_c..k_fin)
#define OFF_ENC OFF_GP   // [64][256] enc lives here between k_s2 and k_z (dead before k_c writes)
#define OFF_SO  176128   // [128] scale[64], offset[64]

// ---------------------------------------------------------------------------
// Fold Wm0 through Wdc:  T2[m][a*3+j] = sum_e Wm0[m,e]*Wdc[e*6+a, j]
//                        V[m*6+a][v]  = sum_e Wm0[m,e]*Wdc[e*6+a, 3+v]
__global__ __launch_bounds__(256) void k_w2(const float* __restrict__ Wm0,
                                            const float* __restrict__ Wdc,
                                            float* __restrict__ ws) {
    int idx = blockIdx.x * 256 + threadIdx.x;
    if (idx < 384 * 128) {
        int ma = idx >> 7, v = idx & 127;
        int a = ma % 6;
        const float* wm = Wm0 + (ma / 6) * 256;   // wave-uniform -> s_load
        float s = 0.f;
#pragma unroll 8
        for (int e = 0; e < 256; ++e)
            s = fmaf(wm[e], Wdc[(e * 6 + a) * 131 + 3 + v], s);
        ws[OFF_V + ma * 128 + v] = s;
    } else if (idx < 384 * 128 + 64 * 18) {
        int j2 = idx - 384 * 128;
        int m = j2 / 18, r = j2 % 18;
        int a = r / 3, j = r % 3;
        const float* wm = Wm0 + m * 256;
        float s = 0.f;
#pragma unroll 8
        for (int e = 0; e < 256; ++e)
            s = fmaf(wm[e], Wdc[(e * 6 + a) * 131 + j], s);
        ws[OFF_T2 + m * 18 + r] = s;
    }
}

// ---------------------------------------------------------------------------
// Stage A: per-batch moments for aggregate().
// M[b][c*6+a] = sum_n dir_in[c]*cos2[a]*dw ;  Sdw[b] = sum_n dw
__global__ __launch_bounds__(256) void k_a(const float* __restrict__ x,
                                           float* __restrict__ ws) {
    __shared__ float red[61 * 257];
    int b = blockIdx.x, t = threadIdx.x;
    float acc[61];
#pragma unroll
    for (int i = 0; i < 61; ++i) acc[i] = 0.f;
    for (int k = 0; k < 8; ++k) {
        int n = t + 256 * k;
        const float* xp = x + (size_t)(b * NPTS + n) * 10;
        float xv[10];
#pragma unroll
        for (int j = 0; j < 5; ++j) {
            float2 v = *(const float2*)(xp + 2 * j);
            xv[2 * j] = v.x; xv[2 * j + 1] = v.y;
        }
        float x0 = xv[0], x1 = xv[1], x2 = xv[2];
        float rn = x0 * x0 + x1 * x1 + x2 * x2;
        float norm = sqrtf(rn);
        float inv = 1.f / (norm + 1e-8f);
        float c2[6];
        c2[0] = fmaxf(x2, 0.f) * inv; c2[1] = fmaxf(-x2, 0.f) * inv;
        c2[2] = fmaxf(x1, 0.f) * inv; c2[3] = fmaxf(-x1, 0.f) * inv;
        c2[4] = fmaxf(x0, 0.f) * inv; c2[5] = fmaxf(-x0, 0.f) * inv;
#pragma unroll
        for (int a = 0; a < 6; ++a) c2[a] *= c2[a];
        float dw = 1.f - (rn - 1.f) * (1.f / 3.f);
        if (dw < 0.f) dw = 0.f;
        if (norm <= 0.f) dw = 0.f;
        float cw[6];
#pragma unroll
        for (int a = 0; a < 6; ++a) cw[a] = c2[a] * dw;
#pragma unroll
        for (int c = 0; c < 10; ++c) {
            float dv = (c < 7) ? xv[3 + c] : xv[c - 7];
#pragma unroll
            for (int a = 0; a < 6; ++a)
                acc[c * 6 + a] = fmaf(dv, cw[a], acc[c * 6 + a]);
        }
        acc[60] += dw;
    }
#pragma unroll
    for (int i = 0; i < 61; ++i) red[i * 257 + t] = acc[i];
    __syncthreads();
    if (t < 61) {
        float s = 0.f;
#pragma unroll 8
        for (int j = 0; j < 256; ++j) s += red[t * 257 + j];
        ws[OFF_M + b * 61 + t] = s;
    }
}

// ---------------------------------------------------------------------------
// Stage B1 (rewritten): all small matrices staged into LDS with coalesced
// batched loads; per-thread weight rows hoisted to registers. R1 version did
// ~2000 serial scattered global loads/thread -> 111 us @ 0.09% VALUBusy.
__global__ __launch_bounds__(256) void k_b1(const float* __restrict__ Wdir,
                                            const float* __restrict__ g1,
                                            const float* __restrict__ b1,
                                            const float* __restrict__ Wdir2,
                                            float* __restrict__ ws) {
    __shared__ float Wd[64 * 61];   // Wdir transposed: [m][a*10+c], stride 61 (conflict-free: 61%32=29, gcd=1)
    __shared__ float Ml[64 * 61];   // M: [b][c*6+a], Sdw at [b][60]
    __shared__ float h1[64 * 64];
    __shared__ float w2[32 * 65];   // Wdir2 tile [e_loc][m], stride 65 -> bank (e+m)%32
    __shared__ float sc[64], of[64];
    int t = threadIdx.x;
    for (int g = t; g < 64 * 61; g += 256) Ml[g] = ws[OFF_M + g];               // coalesced
    for (int g = t; g < 3840; g += 256) Wd[(g / 60) * 61 + g % 60] = Wdir[g];   // coalesced read
    {
        const float* src = Wdir2 + blockIdx.x * 32 * 64;
        for (int g = t; g < 2048; g += 256) w2[(g >> 6) * 65 + (g & 63)] = src[g];
    }
    __syncthreads();
    // h1[b][m]: thread owns m = t&63 for 16 b's -> hoist Wdir row to registers
    int m = t & 63;
    float Wr[60];
#pragma unroll
    for (int r = 0; r < 60; ++r) Wr[r] = Wd[m * 61 + r];
#pragma unroll
    for (int k = 0; k < 16; ++k) {
        int e0 = t + 256 * k;
        int b = e0 >> 6;                      // wave-uniform -> LDS broadcast reads
        const float* Mb = Ml + b * 61;
        float s = 0.f;
#pragma unroll
        for (int a = 0; a < 6; ++a)
#pragma unroll
            for (int c = 0; c < 10; ++c)
                s = fmaf(Wr[a * 10 + c], Mb[c * 6 + a], s);
        h1[e0] = s / Mb[60];
    }
    __syncthreads();
    if (t < 64) {
        float s = 0.f, q = 0.f;
#pragma unroll 8
        for (int b = 0; b < 64; ++b) { float v = h1[b * 64 + t]; s += v; q = fmaf(v, v, q); }
        float mean = s * (1.f / 64.f);
        float var = q * (1.f / 64.f) - mean * mean;
        float scale = g1[t] * rsqrtf(var + 1e-5f);
        sc[t] = scale; of[t] = b1[t] - mean * scale;
    }
    __syncthreads();
#pragma unroll
    for (int k = 0; k < 16; ++k) {
        int e0 = t + 256 * k;
        h1[e0] = fmaxf(fmaf(h1[e0], sc[e0 & 63], of[e0 & 63]), 0.f);
    }
    __syncthreads();
    // d2 = h1 @ Wdir2^T for this block's 32 e-columns; weight row in registers
    int e_loc = t & 31;
    float wr[64];
#pragma unroll
    for (int mm = 0; mm < 64; ++mm) wr[mm] = w2[e_loc * 65 + mm];
    int b0 = t >> 5;
    int e = blockIdx.x * 32 + e_loc;
#pragma unroll
    for (int k = 0; k < 8; ++k) {
        int b = b0 + 8 * k;
        const float* h = h1 + b * 64;         // 2 uniform addrs/wave -> broadcast
        float s = 0.f;
#pragma unroll
        for (int mm = 0; mm < 64; ++mm) s = fmaf(h[mm], wr[mm], s);
        ws[OFF_D2 + b * 256 + e] = s;
    }
}

// ---------------------------------------------------------------------------
// BN2 stats + materialize enc = relu(bn2(d2)) into ws. 1 block; column t per
// thread; all loads coalesced and batched (64 independent loads in flight).
__global__ __launch_bounds__(256) void k_s2(const float* __restrict__ g2,
                                            const float* __restrict__ b2,
                                            float* __restrict__ ws) {
    int t = threadIdx.x;
    float v[64];
#pragma unroll
    for (int b = 0; b < 64; ++b) v[b] = ws[OFF_D2 + b * 256 + t];
    float s = 0.f, q = 0.f;
#pragma unroll
    for (int b = 0; b < 64; ++b) { s += v[b]; q = fmaf(v[b], v[b], q); }
    float mean = s * (1.f / 64.f);
    float var = q * (1.f / 64.f) - mean * mean;
    float scale = g2[t] * rsqrtf(var + 1e-5f);
    float off = b2[t] - mean * scale;
#pragma unroll
    for (int b = 0; b < 64; ++b)
        ws[OFF_ENC + b * 256 + t] = fmaxf(fmaf(v[b], scale, off), 0.f);
}

// ---------------------------------------------------------------------------
// z = enc @ Wf1^T + bf1. 16 blocks, tile 32v x 16b, both operands LDS-staged
// with stride-257 padding (bank = (row+e)%32, conflict-free).
__global__ __launch_bounds__(256) void k_z(const float* __restrict__ Wf1,
                                           const float* __restrict__ bf1,
                                           float* __restrict__ ws) {
    __shared__ float Wl[32 * 257];
    __shared__ float El[16 * 257];
    int t = threadIdx.x;
    int vb = blockIdx.x >> 2, bb = blockIdx.x & 3;
    const float* Wsrc = Wf1 + vb * 32 * 256;
    for (int g = t; g < 32 * 256; g += 256) Wl[(g >> 8) * 257 + (g & 255)] = Wsrc[g];
    const float* Esrc = ws + OFF_ENC + bb * 16 * 256;
    for (int g = t; g < 16 * 256; g += 256) El[(g >> 8) * 257 + (g & 255)] = Esrc[g];
    __syncthreads();
    int v_loc = t & 31, b_loc = t >> 5;
    const float* W  = Wl + v_loc * 257;
    const float* E0 = El + b_loc * 257;
    const float* E1 = El + (b_loc + 8) * 257;
    float s0 = 0.f, s1 = 0.f;
#pragma unroll 8
    for (int e = 0; e < 256; ++e) {
        float w = W[e];
        s0 = fmaf(E0[e], w, s0);
        s1 = fmaf(E1[e], w, s1);
    }
    int v = vb * 32 + v_loc;
    float bias = bf1[v];
    ws[OFF_Z + (bb * 16 + b_loc) * 128 + v] = s0 + bias;
    ws[OFF_Z + (bb * 16 + b_loc + 8) * 128 + v] = s1 + bias;
}

// ---------------------------------------------------------------------------
// U2[ma][b] = z @ V^T  and  center2[b][m] = [z, xyz0] @ Wcm^T + bcm.
// All operands LDS-staged; unioned LDS buffer keeps static LDS under 64 KB.
__global__ __launch_bounds__(256) void k_u(const float* __restrict__ x,
                                           const float* __restrict__ Wcm,
                                           const float* __restrict__ bcm,
                                           float* __restrict__ ws) {
    __shared__ float lds[64 * 133 + 4 * 128 + 12];
    int blk = blockIdx.x, t = threadIdx.x;
    if (blk < 96) {
        float* zl = lds;                 // [64][129] pad -> bank (b+v)%32
        float* Vl = lds + 64 * 129;      // [4][128]
        for (int g = t; g < 8192; g += 256) zl[(g >> 7) * 129 + (g & 127)] = ws[OFF_Z + g];
        const float* Vsrc = ws + OFF_V + blk * 4 * 128;
        for (int g = t; g < 512; g += 256) Vl[g] = Vsrc[g];
        __syncthreads();
        int ma_loc = t >> 6, b = t & 63;
        const float* z = zl + b * 129;   // 2 lanes/bank = free
        const float* v = Vl + ma_loc * 128;  // wave-uniform broadcast
        float s = 0.f;
#pragma unroll 8
        for (int i = 0; i < 128; ++i) s = fmaf(z[i], v[i], s);
        ws[OFF_U2 + (blk * 4 + ma_loc) * 64 + b] = s;
    } else {
        float* Wl  = lds;                // [64][133] pad -> bank (5m+i)%32, gcd(5,32)=1
        float* zl2 = lds + 64 * 133;     // [4][128]
        float* xl  = lds + 64 * 133 + 512;
        int b0 = (blk - 96) * 4;
        for (int g = t; g < 64 * 131; g += 256) Wl[(g / 131) * 133 + g % 131] = Wcm[g];
        for (int g = t; g < 512; g += 256) zl2[g] = ws[OFF_Z + b0 * 128 + g];
        if (t < 12) xl[t] = x[(size_t)(b0 + t / 3) * NPTS * 10 + t % 3];
        __syncthreads();
        int m = t & 63, b_loc = t >> 6;
        const float* w = Wl + m * 133;
        const float* z = zl2 + b_loc * 128;  // wave-uniform broadcast
        float s = bcm[m];
#pragma unroll 8
        for (int i = 0; i < 128; ++i) s = fmaf(z[i], w[i], s);
        s = fmaf(xl[b_loc * 3 + 0], w[128], s);
        s = fmaf(xl[b_loc * 3 + 1], w[129], s);
        s = fmaf(xl[b_loc * 3 + 2], w[130], s);
        ws[OFF_C2 + (b0 + b_loc) * 64 + m] = s;
    }
}

// ---------------------------------------------------------------------------
// Stage C: bn3 statistics. Lane = channel m; wave g owns 64 points; x loads
// are wave-uniform (s_load), batched via unroll.
__global__ __launch_bounds__(256) void k_c(const float* __restrict__ x,
                                           float* __restrict__ ws) {
    __shared__ float r2[512];
    int blk = blockIdx.x;
    int b = blk >> 3, c = blk & 7;
    int t = threadIdx.x;
    int m = t & 63;
    int g = __builtin_amdgcn_readfirstlane(t >> 6);
    float T[18], U[6];
    const float* t2 = ws + OFF_T2 + m * 18;
#pragma unroll
    for (int r = 0; r < 18; ++r) T[r] = t2[r];
#pragma unroll
    for (int a = 0; a < 6; ++a) U[a] = ws[OFF_U2 + (m * 6 + a) * 64 + b];
    bool has0 = (c == 0) && (g == 0);
    float c2v = 0.f;
    if (has0) c2v = ws[OFF_C2 + b * 64 + m];
    float accS = 0.f, accQ = 0.f;
    int p0 = c * 256 + g * 64;
    const float* xb = x + (size_t)b * NPTS * 10;
#pragma unroll 4
    for (int i = 0; i < 64; ++i) {
        const float* xp = xb + (p0 + i) * 10;     // wave-uniform address
        float x0 = xp[0], x1 = xp[1], x2 = xp[2];
        float rn = x0 * x0 + x1 * x1 + x2 * x2;
        float inv = 1.f / (sqrtf(rn) + 1e-8f);
        float c2[6];
        c2[0] = fmaxf(x2, 0.f) * inv; c2[1] = fmaxf(-x2, 0.f) * inv;
        c2[2] = fmaxf(x1, 0.f) * inv; c2[3] = fmaxf(-x1, 0.f) * inv;
        c2[4] = fmaxf(x0, 0.f) * inv; c2[5] = fmaxf(-x0, 0.f) * inv;
        float h = 0.f;
#pragma unroll
        for (int a = 0; a < 6; ++a) {
            float cc = c2[a] * c2[a];
            float ta = fmaf(x0, T[a * 3], fmaf(x1, T[a * 3 + 1], fmaf(x2, T[a * 3 + 2], U[a])));
            h = fmaf(cc, ta, h);
        }
        if (has0 && i == 0) h = c2v;
        accS += h;
        accQ = fmaf(h, h, accQ);
    }
    r2[t] = accS; r2[256 + t] = accQ;
    __syncthreads();
    if (t < 64) {
        ws[OFF_GP + blk * 128 + t] = r2[t] + r2[64 + t] + r2[128 + t] + r2[192 + t];
    } else if (t < 128) {
        int mm = t - 64;
        ws[OFF_GP + blk * 128 + t] = r2[256 + mm] + r2[320 + mm] + r2[384 + mm] + r2[448 + mm];
    }
}

// ---------------------------------------------------------------------------
// Finalize BN3: 256 threads (4 groups x 128 partials), batched coalesced.
__global__ __launch_bounds__(256) void k_fin(const float* __restrict__ g3,
                                             const float* __restrict__ b3,
                                             float* __restrict__ ws) {
    __shared__ float r[512];
    int t = threadIdx.x;
    int m = t & 63, g = t >> 6;
    float s = 0.f, q = 0.f;
#pragma unroll 8
    for (int j = 0; j < 128; ++j) {
        int blk = g * 128 + j;
        s += ws[OFF_GP + blk * 128 + m];
        q += ws[OFF_GP + blk * 128 + 64 + m];
    }
    r[t] = s; r[256 + t] = q;
    __syncthreads();
    if (t < 64) {
        float S = r[t] + r[64 + t] + r[128 + t] + r[192 + t];
        float Q = r[256 + t] + r[320 + t] + r[384 + t] + r[448 + t];
        float mean = S * (1.f / 131072.f);
        float var = Q * (1.f / 131072.f) - mean * mean;
        float scale = g3[t] * rsqrtf(var + 1e-5f);
        ws[OFF_SO + t] = scale;
        ws[OFF_SO + 64 + t] = b3[t] - mean * scale;
    }
}

// ---------------------------------------------------------------------------
// Stage E: recompute sig2 per point, BN3+relu, @Wf2.T+bf2, sigmoid.
__global__ __launch_bounds__(256) void k_e(const float* __restrict__ x,
                                           const float* __restrict__ Wf2,
                                           const float* __restrict__ bf2,
                                           const float* __restrict__ ws,
                                           float* __restrict__ out) {
    int idx = blockIdx.x * 256 + threadIdx.x;
    int b = idx >> 11, n = idx & 2047;
    const float* xp = x + (size_t)idx * 10;
    float x0 = xp[0], x1 = xp[1], x2 = xp[2];
    float rn = x0 * x0 + x1 * x1 + x2 * x2;
    float inv = 1.f / (sqrtf(rn) + 1e-8f);
    float c2[6];
    c2[0] = fmaxf(x2, 0.f) * inv; c2[1] = fmaxf(-x2, 0.f) * inv;
    c2[2] = fmaxf(x1, 0.f) * inv; c2[3] = fmaxf(-x1, 0.f) * inv;
    c2[4] = fmaxf(x0, 0.f) * inv; c2[5] = fmaxf(-x0, 0.f) * inv;
#pragma unroll
    for (int a = 0; a < 6; ++a) c2[a] *= c2[a];
    bool c0 = (n == 0);
    float y[7];
#pragma unroll
    for (int k = 0; k < 7; ++k) y[k] = bf2[k];
    const float* T2 = ws + OFF_T2;
    const float* U2 = ws + OFF_U2;
    const float* SO = ws + OFF_SO;
    const float* C2W = ws + OFF_C2 + b * 64;
    for (int m = 0; m < 64; ++m) {
        float h = 0.f;
#pragma unroll
        for (int a = 0; a < 6; ++a) {
            float ta = fmaf(x0, T2[m * 18 + a * 3],
                       fmaf(x1, T2[m * 18 + a * 3 + 1],
                       fmaf(x2, T2[m * 18 + a * 3 + 2], U2[(m * 6 + a) * 64 + b])));
            h = fmaf(c2[a], ta, h);
        }
        if (c0) h = C2W[m];
        float tt = fmaf(h, SO[m], SO[64 + m]);
        float r = fmaxf(tt, 0.f);
#pragma unroll
        for (int k = 0; k < 7; ++k) y[k] = fmaf(r, Wf2[k * 64 + m], y[k]);
    }
    float* op = out + (size_t)idx * 7;
#pragma unroll
    for (int k = 0; k < 7; ++k) op[k] = 1.f / (1.f + __expf(-y[k]));
}

// ---------------------------------------------------------------------------
extern "C" void kernel_launch(void* const* d_in, const int* in_sizes, int n_in,
                              void* d_out, int out_size, void* d_ws, size_t ws_size,
                              hipStream_t stream) {
    const float* x     = (const float*)d_in[0];
    // d_in[1]=Wc, d_in[2]=bc : dead code in reference (center is unused)
    const float* Wdir  = (const float*)d_in[3];
    const float* g1    = (const float*)d_in[4];
    const float* b1    = (const float*)d_in[5];
    const float* Wdir2 = (const float*)d_in[6];
    const float* g2    = (const float*)d_in[7];
    const float* b2    = (const float*)d_in[8];
    const float* Wf1   = (const float*)d_in[9];
    const float* bf1   = (const float*)d_in[10];
    const float* Wcm   = (const float*)d_in[11];
    const float* bcm   = (const float*)d_in[12];
    const float* Wdc   = (const float*)d_in[13];
    const float* Wm0   = (const float*)d_in[14];
    const float* g3    = (const float*)d_in[15];
    const float* b3    = (const float*)d_in[16];
    const float* Wf2   = (const float*)d_in[17];
    const float* bf2   = (const float*)d_in[18];
    float* ws  = (float*)d_ws;
    float* out = (float*)d_out;

    k_w2 <<<197, 256, 0, stream>>>(Wm0, Wdc, ws);
    k_a  <<<64,  256, 0, stream>>>(x, ws);
    k_b1 <<<8,   256, 0, stream>>>(Wdir, g1, b1, Wdir2, ws);
    k_s2 <<<1,   256, 0, stream>>>(g2, b2, ws);
    k_z  <<<16,  256, 0, stream>>>(Wf1, bf1, ws);
    k_u  <<<112, 256, 0, stream>>>(x, Wcm, bcm, ws);
    k_c  <<<512, 256, 0, stream>>>(x, ws);
    k_fin<<<1,   256, 0, stream>>>(g3, b3, ws);
    k_e  <<<512, 256, 0, stream>>>(x, Wf2, bf2, ws, out);
}